// Round 1
// baseline (387.571 us; speedup 1.0000x reference)
//
#include <hip/hip_runtime.h>
#include <math.h>

typedef unsigned short u16;
typedef __attribute__((ext_vector_type(8))) short bf16x8;
typedef __attribute__((ext_vector_type(4))) float f32x4;

#define S_LEN 2048
#define D_MODEL 1024
#define N_HEADS 16
#define D_HEAD 64
#define F_MLP 4096
#define N_QKV 3072

__device__ __forceinline__ u16 f2b(float f) {
    union { float f; unsigned u; } x; x.f = f;
    unsigned r = x.u + 0x7fffu + ((x.u >> 16) & 1u);
    return (u16)(r >> 16);
}

// ---------------- bias concat: [b_Q | b_K | b_V] -> qkvb[3072] ----------------
__global__ void concat_bias(const float* __restrict__ bq, const float* __restrict__ bk,
                            const float* __restrict__ bv, float* __restrict__ out) {
    int i = blockIdx.x * 256 + threadIdx.x;
    float v = (i < 1024) ? bq[i] : (i < 2048) ? bk[i - 1024] : bv[i - 2048];
    out[i] = v;
}

// ---------------- transpose f32 [R][C] -> bf16 [C][out_ld>=R], batched ----------------
__global__ void transpose_f32_bf16(const float* __restrict__ in, u16* __restrict__ out,
                                   int R, int C, int out_ld, long in_bstride, int out_brow) {
    __shared__ float t[32][33];
    int b = blockIdx.z;
    const float* src = in + (long)b * in_bstride;
    u16* dst = out + (long)b * out_brow * out_ld;
    int c0 = blockIdx.x * 32, r0 = blockIdx.y * 32;
    int tx = threadIdx.x, ty = threadIdx.y;   // 32 x 8
    #pragma unroll
    for (int i = 0; i < 32; i += 8)
        t[ty + i][tx] = src[(long)(r0 + ty + i) * C + c0 + tx];
    __syncthreads();
    #pragma unroll
    for (int i = 0; i < 32; i += 8)
        dst[(long)(c0 + ty + i) * out_ld + r0 + tx] = f2b(t[tx][ty + i]);
}

// ---------------- layernorm f32 [S][1024] -> bf16, one block per row ----------------
__global__ __launch_bounds__(256) void layernorm_bf16(const float* __restrict__ x,
                                                      const float* __restrict__ w,
                                                      const float* __restrict__ b,
                                                      u16* __restrict__ out) {
    int row = blockIdx.x, tid = threadIdx.x;
    const float4* xr = (const float4*)(x + (long)row * D_MODEL);
    float4 v = xr[tid];
    float s = v.x + v.y + v.z + v.w;
    float ss = v.x * v.x + v.y * v.y + v.z * v.z + v.w * v.w;
    #pragma unroll
    for (int o = 1; o < 64; o <<= 1) { s += __shfl_xor(s, o, 64); ss += __shfl_xor(ss, o, 64); }
    __shared__ float sh[8];
    int wave = tid >> 6, lane = tid & 63;
    if (lane == 0) { sh[wave] = s; sh[4 + wave] = ss; }
    __syncthreads();
    s = sh[0] + sh[1] + sh[2] + sh[3];
    ss = sh[4] + sh[5] + sh[6] + sh[7];
    float mu = s * (1.0f / D_MODEL);
    float var = ss * (1.0f / D_MODEL) - mu * mu;
    float rstd = rsqrtf(var + 1e-5f);
    float4 wv = ((const float4*)w)[tid];
    float4 bv = ((const float4*)b)[tid];
    u16 o4[4];
    o4[0] = f2b((v.x - mu) * rstd * wv.x + bv.x);
    o4[1] = f2b((v.y - mu) * rstd * wv.y + bv.y);
    o4[2] = f2b((v.z - mu) * rstd * wv.z + bv.z);
    o4[3] = f2b((v.w - mu) * rstd * wv.w + bv.w);
    *(ushort4*)(out + (long)row * D_MODEL + tid * 4) = *(ushort4*)o4;
}

// ---------------- GEMM: C[M][N] = A[M][K](bf16) * BT[N][K](bf16)^T + bias ----------------
// MODE 0: out bf16 = v + bias
// MODE 1: out f32  = v + bias + addend
// MODE 2: out bf16 = gelu_tanh(v + bias)
template <int MODE>
__global__ __launch_bounds__(256) void gemm_bt(const u16* __restrict__ A,
                                               const u16* __restrict__ BT,
                                               const float* __restrict__ bias,
                                               const float* __restrict__ addend,
                                               void* __restrict__ Cout,
                                               int M, int N, int K) {
    __shared__ u16 As[128][40];
    __shared__ u16 Bs[128][40];
    const int bm = blockIdx.y * 128, bn = blockIdx.x * 128;
    const int tid = threadIdx.x;
    const int wave = tid >> 6, lane = tid & 63;
    const int wm = (wave >> 1) * 64, wn = (wave & 1) * 64;
    const int l16 = lane & 15, lq = lane >> 4;

    f32x4 acc[4][4] = {};

    for (int k0 = 0; k0 < K; k0 += 32) {
        #pragma unroll
        for (int c = 0; c < 2; ++c) {
            int chunk = tid + c * 256;
            int r = chunk >> 2, col = (chunk & 3) * 8;
            bf16x8 va = *(const bf16x8*)(A + (long)(bm + r) * K + k0 + col);
            bf16x8 vb = *(const bf16x8*)(BT + (long)(bn + r) * K + k0 + col);
            *(bf16x8*)&As[r][col] = va;
            *(bf16x8*)&Bs[r][col] = vb;
        }
        __syncthreads();
        bf16x8 af[4], bf[4];
        #pragma unroll
        for (int i = 0; i < 4; ++i) {
            af[i] = *(const bf16x8*)&As[wm + i * 16 + l16][lq * 8];
            bf[i] = *(const bf16x8*)&Bs[wn + i * 16 + l16][lq * 8];
        }
        #pragma unroll
        for (int i = 0; i < 4; ++i)
            #pragma unroll
            for (int j = 0; j < 4; ++j)
                acc[i][j] = __builtin_amdgcn_mfma_f32_16x16x32_bf16(af[i], bf[j], acc[i][j], 0, 0, 0);
        __syncthreads();
    }

    #pragma unroll
    for (int i = 0; i < 4; ++i) {
        int row = bm + wm + i * 16 + lq * 4;
        #pragma unroll
        for (int j = 0; j < 4; ++j) {
            int col = bn + wn + j * 16 + l16;
            float bcol = bias[col];
            #pragma unroll
            for (int r = 0; r < 4; ++r) {
                float v = acc[i][j][r] + bcol;
                long idx = (long)(row + r) * N + col;
                if (MODE == 0) {
                    ((u16*)Cout)[idx] = f2b(v);
                } else if (MODE == 1) {
                    ((float*)Cout)[idx] = v + addend[idx];
                } else {
                    float g = 0.5f * v * (1.0f + tanhf(0.7978845608028654f * (v + 0.044715f * v * v * v)));
                    ((u16*)Cout)[idx] = f2b(g);
                }
            }
        }
    }
}

// ---------------- causal flash attention ----------------
// qkv bf16 [S][3072]: cols [0,1024)=Q, [1024,2048)=K, [2048,3072)=V (per head h: h*64..h*64+63)
// z bf16 [S][1024]
__global__ __launch_bounds__(256) void attn_kernel(const u16* __restrict__ qkv,
                                                   const float* __restrict__ mask_logits,
                                                   u16* __restrict__ z) {
    const int h = blockIdx.y;
    const int qt = blockIdx.x;              // 64 q rows per block
    const int tid = threadIdx.x;
    const int wave = tid >> 6, lane = tid & 63;
    const int l16 = lane & 15, lq = lane >> 4;
    const int qb = qt * 64 + wave * 16;     // this wave's 16 q rows

    __shared__ u16 Vt[64][40];              // [dh][sk], padded
    __shared__ u16 P[4][16][40];            // per-wave P tile [q][sk]

    const int QC = h * 64, KC = 1024 + h * 64, VC = 2048 + h * 64;

    bf16x8 qf[2];
    #pragma unroll
    for (int kc = 0; kc < 2; ++kc)
        qf[kc] = *(const bf16x8*)(qkv + (long)(qb + l16) * N_QKV + QC + kc * 32 + lq * 8);

    f32x4 accz[4] = {};
    float mrow[4], lrow[4];
    #pragma unroll
    for (int r = 0; r < 4; ++r) { mrow[r] = -3.0e38f; lrow[r] = 0.0f; }

    const int ntiles = qt * 2 + 2;
    for (int t = 0; t < ntiles; ++t) {
        int sk0 = t * 32;
        // stage V^T into LDS
        {
            int sk = tid >> 3, d0 = (tid & 7) * 8;
            bf16x8 v = *(const bf16x8*)(qkv + (long)(sk0 + sk) * N_QKV + VC + d0);
            #pragma unroll
            for (int j = 0; j < 8; ++j) Vt[d0 + j][sk] = (u16)v[j];
        }
        __syncthreads();

        // scores = Q K^T * 0.125 with causal mask
        f32x4 sfrag[2];
        #pragma unroll
        for (int nf = 0; nf < 2; ++nf) {
            f32x4 accs = {};
            #pragma unroll
            for (int kc = 0; kc < 2; ++kc) {
                bf16x8 kf = *(const bf16x8*)(qkv + (long)(sk0 + nf * 16 + l16) * N_QKV + KC + kc * 32 + lq * 8);
                accs = __builtin_amdgcn_mfma_f32_16x16x32_bf16(qf[kc], kf, accs, 0, 0, 0);
            }
            sfrag[nf] = accs;
        }
        float mt[4];
        #pragma unroll
        for (int r = 0; r < 4; ++r) mt[r] = -3.0e38f;
        #pragma unroll
        for (int nf = 0; nf < 2; ++nf) {
            int sk = sk0 + nf * 16 + l16;
            #pragma unroll
            for (int r = 0; r < 4; ++r) {
                int qrow = qb + lq * 4 + r;
                float s = sfrag[nf][r] * 0.125f;
                s = (sk <= qrow) ? s : -3.0e38f;
                sfrag[nf][r] = s;
                mt[r] = fmaxf(mt[r], s);
            }
        }
        #pragma unroll
        for (int o = 1; o < 16; o <<= 1)
            #pragma unroll
            for (int r = 0; r < 4; ++r)
                mt[r] = fmaxf(mt[r], __shfl_xor(mt[r], o, 64));

        float rs[4];
        #pragma unroll
        for (int r = 0; r < 4; ++r) {
            float mnew = fmaxf(mrow[r], mt[r]);
            float f = __expf(mrow[r] - mnew);
            mrow[r] = mnew;
            lrow[r] *= f;
            rs[r] = f;
        }
        #pragma unroll
        for (int nf2 = 0; nf2 < 4; ++nf2)
            #pragma unroll
            for (int r = 0; r < 4; ++r)
                accz[nf2][r] *= rs[r];

        float pr[2][4];
        float lt[4] = {0.f, 0.f, 0.f, 0.f};
        #pragma unroll
        for (int nf = 0; nf < 2; ++nf)
            #pragma unroll
            for (int r = 0; r < 4; ++r) {
                float p = __expf(sfrag[nf][r] - mrow[r]);
                lt[r] += p;
                pr[nf][r] = p;
            }
        #pragma unroll
        for (int o = 1; o < 16; o <<= 1)
            #pragma unroll
            for (int r = 0; r < 4; ++r)
                lt[r] += __shfl_xor(lt[r], o, 64);
        #pragma unroll
        for (int r = 0; r < 4; ++r) lrow[r] += lt[r];

        // P (C-layout) -> LDS -> A-layout
        #pragma unroll
        for (int nf = 0; nf < 2; ++nf)
            #pragma unroll
            for (int r = 0; r < 4; ++r)
                P[wave][lq * 4 + r][nf * 16 + l16] = f2b(pr[nf][r]);
        bf16x8 pf = *(const bf16x8*)&P[wave][l16][lq * 8];

        #pragma unroll
        for (int nf2 = 0; nf2 < 4; ++nf2) {
            bf16x8 vf = *(const bf16x8*)&Vt[nf2 * 16 + l16][lq * 8];
            accz[nf2] = __builtin_amdgcn_mfma_f32_16x16x32_bf16(pf, vf, accz[nf2], 0, 0, 0);
        }
        __syncthreads();
    }

    float gate = (mask_logits[h] > 0.0f) ? 1.0f : 0.0f;
    #pragma unroll
    for (int r = 0; r < 4; ++r) {
        float inv = gate / lrow[r];
        int row = qb + lq * 4 + r;
        #pragma unroll
        for (int nf2 = 0; nf2 < 4; ++nf2)
            z[(long)row * D_MODEL + h * 64 + nf2 * 16 + l16] = f2b(accz[nf2][r] * inv);
    }
}

// ---------------- launcher ----------------
extern "C" void kernel_launch(void* const* d_in, const int* in_sizes, int n_in,
                              void* d_out, int out_size, void* d_ws, size_t ws_size,
                              hipStream_t stream) {
    const float* resid_pre  = (const float*)d_in[0];
    const float* ln1_w      = (const float*)d_in[1];
    const float* ln1_b      = (const float*)d_in[2];
    const float* W_Q        = (const float*)d_in[3];
    const float* b_Q        = (const float*)d_in[4];
    const float* W_K        = (const float*)d_in[5];
    const float* b_K        = (const float*)d_in[6];
    const float* W_V        = (const float*)d_in[7];
    const float* b_V        = (const float*)d_in[8];
    const float* W_O        = (const float*)d_in[9];
    const float* b_O        = (const float*)d_in[10];
    const float* mask_logits= (const float*)d_in[11];
    const float* ln2_w      = (const float*)d_in[12];
    const float* ln2_b      = (const float*)d_in[13];
    const float* W_in       = (const float*)d_in[14];
    const float* b_in       = (const float*)d_in[15];
    const float* W_out      = (const float*)d_in[16];
    const float* b_out      = (const float*)d_in[17];

    char* p = (char*)d_ws;
    u16* WT_qkv = (u16*)p; p += (size_t)N_QKV * D_MODEL * 2;        // [3072][1024]
    u16* WT_O   = (u16*)p; p += (size_t)D_MODEL * D_MODEL * 2;      // [1024][1024]
    u16* WT_in  = (u16*)p; p += (size_t)F_MLP * D_MODEL * 2;        // [4096][1024]
    u16* WT_out = (u16*)p; p += (size_t)D_MODEL * F_MLP * 2;        // [1024][4096]
    float* qkvb = (float*)p; p += (size_t)N_QKV * 4;
    u16* xln    = (u16*)p; p += (size_t)S_LEN * D_MODEL * 2;
    u16* qkv    = (u16*)p; p += (size_t)S_LEN * N_QKV * 2;
    u16* zb     = (u16*)p; p += (size_t)S_LEN * D_MODEL * 2;
    float* rmid = (float*)p; p += (size_t)S_LEN * D_MODEL * 4;
    u16* mb     = (u16*)p; p += (size_t)S_LEN * D_MODEL * 2;
    u16* hb     = (u16*)p; p += (size_t)S_LEN * F_MLP * 2;

    dim3 tb(32, 8, 1);
    concat_bias<<<12, 256, 0, stream>>>(b_Q, b_K, b_V, qkvb);
    // W_Q/K/V [16][1024][64] -> WT_qkv rows h*64+dh
    transpose_f32_bf16<<<dim3(2, 32, 16), tb, 0, stream>>>(W_Q, WT_qkv,                    1024, 64, 1024, 65536L, 64);
    transpose_f32_bf16<<<dim3(2, 32, 16), tb, 0, stream>>>(W_K, WT_qkv + 1024 * D_MODEL,   1024, 64, 1024, 65536L, 64);
    transpose_f32_bf16<<<dim3(2, 32, 16), tb, 0, stream>>>(W_V, WT_qkv + 2048 * D_MODEL,   1024, 64, 1024, 65536L, 64);
    transpose_f32_bf16<<<dim3(32, 32, 1), tb, 0, stream>>>(W_O,  WT_O,   1024, 1024, 1024, 0L, 0);
    transpose_f32_bf16<<<dim3(128, 32, 1), tb, 0, stream>>>(W_in, WT_in,  1024, 4096, 1024, 0L, 0);
    transpose_f32_bf16<<<dim3(32, 128, 1), tb, 0, stream>>>(W_out, WT_out, 4096, 1024, 4096, 0L, 0);

    layernorm_bf16<<<S_LEN, 256, 0, stream>>>(resid_pre, ln1_w, ln1_b, xln);

    gemm_bt<0><<<dim3(N_QKV / 128, S_LEN / 128), 256, 0, stream>>>(xln, WT_qkv, qkvb, nullptr, qkv, S_LEN, N_QKV, D_MODEL);

    attn_kernel<<<dim3(S_LEN / 64, N_HEADS), 256, 0, stream>>>(qkv, mask_logits, zb);

    gemm_bt<1><<<dim3(D_MODEL / 128, S_LEN / 128), 256, 0, stream>>>(zb, WT_O, b_O, resid_pre, rmid, S_LEN, D_MODEL, D_MODEL);

    layernorm_bf16<<<S_LEN, 256, 0, stream>>>(rmid, ln2_w, ln2_b, mb);

    gemm_bt<2><<<dim3(F_MLP / 128, S_LEN / 128), 256, 0, stream>>>(mb, WT_in, b_in, nullptr, hb, S_LEN, F_MLP, D_MODEL);

    gemm_bt<1><<<dim3(D_MODEL / 128, S_LEN / 128), 256, 0, stream>>>(hb, WT_out, b_out, rmid, (float*)d_out, S_LEN, D_MODEL, F_MLP);
}

// Round 2
// 289.783 us; speedup vs baseline: 1.3375x; 1.3375x over previous
//
#include <hip/hip_runtime.h>
#include <math.h>

typedef unsigned short u16;
typedef __attribute__((ext_vector_type(8))) short bf16x8;
typedef __attribute__((ext_vector_type(4))) float f32x4;

#define S_LEN 2048
#define D_MODEL 1024
#define N_HEADS 16
#define D_HEAD 64
#define F_MLP 4096
#define N_QKV 3072
#define QK_LD 2048

__device__ __forceinline__ u16 f2b(float f) {
    union { float f; unsigned u; } x; x.f = f;
    unsigned r = x.u + 0x7fffu + ((x.u >> 16) & 1u);
    return (u16)(r >> 16);
}

__device__ __forceinline__ void gload_lds16(const u16* g, u16* l) {
    __builtin_amdgcn_global_load_lds((const __attribute__((address_space(1))) unsigned int*)g,
                                     (__attribute__((address_space(3))) unsigned int*)l, 16, 0, 0);
}

// ---------------- bias concat: [b_Q | b_K | b_V] -> qkvb[3072] ----------------
__global__ void concat_bias(const float* __restrict__ bq, const float* __restrict__ bk,
                            const float* __restrict__ bv, float* __restrict__ out) {
    int i = blockIdx.x * 256 + threadIdx.x;
    float v = (i < 1024) ? bq[i] : (i < 2048) ? bk[i - 1024] : bv[i - 2048];
    out[i] = v;
}

// ---------------- transpose f32 [R][C] -> bf16 [C][out_ld>=R], batched ----------------
__global__ void transpose_f32_bf16(const float* __restrict__ in, u16* __restrict__ out,
                                   int R, int C, int out_ld, long in_bstride, int out_brow) {
    __shared__ float t[32][33];
    int b = blockIdx.z;
    const float* src = in + (long)b * in_bstride;
    u16* dst = out + (long)b * out_brow * out_ld;
    int c0 = blockIdx.x * 32, r0 = blockIdx.y * 32;
    int tx = threadIdx.x, ty = threadIdx.y;   // 32 x 8
    #pragma unroll
    for (int i = 0; i < 32; i += 8)
        t[ty + i][tx] = src[(long)(r0 + ty + i) * C + c0 + tx];
    __syncthreads();
    #pragma unroll
    for (int i = 0; i < 32; i += 8)
        dst[(long)(c0 + ty + i) * out_ld + r0 + tx] = f2b(t[tx][ty + i]);
}

// ---------------- layernorm f32 [S][1024] -> bf16, one block per row ----------------
__global__ __launch_bounds__(256) void layernorm_bf16(const float* __restrict__ x,
                                                      const float* __restrict__ w,
                                                      const float* __restrict__ b,
                                                      u16* __restrict__ out) {
    int row = blockIdx.x, tid = threadIdx.x;
    const float4* xr = (const float4*)(x + (long)row * D_MODEL);
    float4 v = xr[tid];
    float s = v.x + v.y + v.z + v.w;
    float ss = v.x * v.x + v.y * v.y + v.z * v.z + v.w * v.w;
    #pragma unroll
    for (int o = 1; o < 64; o <<= 1) { s += __shfl_xor(s, o, 64); ss += __shfl_xor(ss, o, 64); }
    __shared__ float sh[8];
    int wave = tid >> 6, lane = tid & 63;
    if (lane == 0) { sh[wave] = s; sh[4 + wave] = ss; }
    __syncthreads();
    s = sh[0] + sh[1] + sh[2] + sh[3];
    ss = sh[4] + sh[5] + sh[6] + sh[7];
    float mu = s * (1.0f / D_MODEL);
    float var = ss * (1.0f / D_MODEL) - mu * mu;
    float rstd = rsqrtf(var + 1e-5f);
    float4 wv = ((const float4*)w)[tid];
    float4 bv = ((const float4*)b)[tid];
    u16 o4[4];
    o4[0] = f2b((v.x - mu) * rstd * wv.x + bv.x);
    o4[1] = f2b((v.y - mu) * rstd * wv.y + bv.y);
    o4[2] = f2b((v.z - mu) * rstd * wv.z + bv.z);
    o4[3] = f2b((v.w - mu) * rstd * wv.w + bv.w);
    *(ushort4*)(out + (long)row * D_MODEL + tid * 4) = *(ushort4*)o4;
}

// ---------------- GEMM: C[M][N] = A[M][K](bf16) * BT[N][K](bf16)^T + bias ----------------
// MODE 0: QKV special — cols [0,2048) -> Cout bf16 (ld 2048), Q part scaled by 0.125;
//                        cols [2048,3072) -> vt transposed: vt[col-2048][row]
// MODE 1: out f32  = v + bias + addend
// MODE 2: out bf16 = gelu_tanh(v + bias)
template <int MODE>
__global__ __launch_bounds__(256) void gemm_bt(const u16* __restrict__ A,
                                               const u16* __restrict__ BT,
                                               const float* __restrict__ bias,
                                               const float* __restrict__ addend,
                                               void* __restrict__ Cout,
                                               u16* __restrict__ vt,
                                               int M, int N, int K) {
    __shared__ u16 As[128 * 32];
    __shared__ u16 Bs[128 * 32];
    const int bm = blockIdx.y * 128, bn = blockIdx.x * 128;
    const int tid = threadIdx.x;
    const int wave = tid >> 6, lane = tid & 63;
    const int wm = (wave >> 1) * 64, wn = (wave & 1) * 64;
    const int l16 = lane & 15, lq = lane >> 4;
    const int srow = lane >> 2, scol = (lane & 3) * 8;   // 16B per lane, 16 rows x 32 cols per wave-chunk

    f32x4 acc[4][4] = {};

    for (int k0 = 0; k0 < K; k0 += 32) {
        #pragma unroll
        for (int c = 0; c < 2; ++c) {
            const int rbase = (wave * 2 + c) * 16;
            gload_lds16(A  + (size_t)(bm + rbase + srow) * K + k0 + scol, As + rbase * 32);
            gload_lds16(BT + (size_t)(bn + rbase + srow) * K + k0 + scol, Bs + rbase * 32);
        }
        __syncthreads();
        bf16x8 af[4], bf[4];
        #pragma unroll
        for (int i = 0; i < 4; ++i) {
            af[i] = *(const bf16x8*)&As[(wm + i * 16 + l16) * 32 + lq * 8];
            bf[i] = *(const bf16x8*)&Bs[(wn + i * 16 + l16) * 32 + lq * 8];
        }
        #pragma unroll
        for (int i = 0; i < 4; ++i)
            #pragma unroll
            for (int j = 0; j < 4; ++j)
                acc[i][j] = __builtin_amdgcn_mfma_f32_16x16x32_bf16(af[i], bf[j], acc[i][j], 0, 0, 0);
        __syncthreads();
    }

    #pragma unroll
    for (int i = 0; i < 4; ++i) {
        const int row = bm + wm + i * 16 + lq * 4;
        #pragma unroll
        for (int j = 0; j < 4; ++j) {
            const int col = bn + wn + j * 16 + l16;
            const float bcol = bias[col];
            if (MODE == 0) {
                if (col < 2048) {
                    const float sc = (col < 1024) ? 0.125f : 1.0f;
                    #pragma unroll
                    for (int r = 0; r < 4; ++r)
                        ((u16*)Cout)[(size_t)(row + r) * QK_LD + col] = f2b((acc[i][j][r] + bcol) * sc);
                } else {
                    u16 tmp[4];
                    #pragma unroll
                    for (int r = 0; r < 4; ++r) tmp[r] = f2b(acc[i][j][r] + bcol);
                    *(ushort4*)(vt + (size_t)(col - 2048) * S_LEN + row) = *(const ushort4*)tmp;
                }
            } else if (MODE == 1) {
                #pragma unroll
                for (int r = 0; r < 4; ++r) {
                    const size_t idx = (size_t)(row + r) * N + col;
                    ((float*)Cout)[idx] = acc[i][j][r] + bcol + addend[idx];
                }
            } else {
                #pragma unroll
                for (int r = 0; r < 4; ++r) {
                    float v = acc[i][j][r] + bcol;
                    float g_ = 0.5f * v * (1.0f + tanhf(0.7978845608028654f * (v + 0.044715f * v * v * v)));
                    ((u16*)Cout)[(size_t)(row + r) * N + col] = f2b(g_);
                }
            }
        }
    }
}

// ---------------- causal flash attention, wave-independent, no barriers ----------------
// qk bf16 [S][2048]: cols [0,1024)=Q*0.125 (scale pre-folded), [1024,2048)=K
// vT bf16 [1024][S]: row h*64+dh, col s
// z  bf16 [S][1024]
__global__ __launch_bounds__(256) void attn_kernel(const u16* __restrict__ qk,
                                                   const u16* __restrict__ vT,
                                                   const float* __restrict__ mask_logits,
                                                   u16* __restrict__ z) {
    const int tid = threadIdx.x;
    const int wave = tid >> 6, lane = tid & 63;
    const int l16 = lane & 15, lq = lane >> 4;
    const int b = blockIdx.x;
    const int h = b & 15, g = b >> 4;                 // g in [0,32)
    // balanced q-tile assignment: per-block work is constant
    int qi = (wave == 0) ? g : (wave == 1) ? (63 - g) : (wave == 2) ? (64 + g) : (127 - g);
    const int qb = qi * 16;
    const int QC = h * 64, KC = 1024 + h * 64;
    const u16* vh = vT + (size_t)(h * 64) * S_LEN;

    __shared__ u16 Pb[4][16][72];                     // per-wave P tile, padded

    bf16x8 qf[2];
    #pragma unroll
    for (int kc = 0; kc < 2; ++kc)
        qf[kc] = *(const bf16x8*)(qk + (size_t)(qb + l16) * QK_LD + QC + kc * 32 + lq * 8);

    f32x4 acc[4] = {};
    float m[4], lsum[4];
    #pragma unroll
    for (int r = 0; r < 4; ++r) { m[r] = -3.0e38f; lsum[r] = 0.0f; }

    const int nt = (qb + 16 + 63) >> 6;               // 64-key tiles
    for (int t = 0; t < nt; ++t) {
        const int sk0 = t << 6;

        // S = Q K^T (scale already folded into Q)
        f32x4 s[4];
        #pragma unroll
        for (int nf = 0; nf < 4; ++nf) {
            f32x4 a = {};
            #pragma unroll
            for (int kc = 0; kc < 2; ++kc) {
                bf16x8 kf = *(const bf16x8*)(qk + (size_t)(sk0 + nf * 16 + l16) * QK_LD + KC + kc * 32 + lq * 8);
                a = __builtin_amdgcn_mfma_f32_16x16x32_bf16(qf[kc], kf, a, 0, 0, 0);
            }
            s[nf] = a;
        }

        // causal mask: only the final tile straddles the diagonal
        if (t == nt - 1) {
            #pragma unroll
            for (int nf = 0; nf < 4; ++nf) {
                const int sk = sk0 + nf * 16 + l16;
                #pragma unroll
                for (int r = 0; r < 4; ++r) {
                    const int qrow = qb + lq * 4 + r;
                    s[nf][r] = (sk <= qrow) ? s[nf][r] : -3.0e38f;
                }
            }
        }

        float mt[4];
        #pragma unroll
        for (int r = 0; r < 4; ++r)
            mt[r] = fmaxf(fmaxf(s[0][r], s[1][r]), fmaxf(s[2][r], s[3][r]));
        #pragma unroll
        for (int o = 1; o < 16; o <<= 1)
            #pragma unroll
            for (int r = 0; r < 4; ++r)
                mt[r] = fmaxf(mt[r], __shfl_xor(mt[r], o, 64));

        float rs[4];
        #pragma unroll
        for (int r = 0; r < 4; ++r) {
            const float mnew = fmaxf(m[r], mt[r]);
            rs[r] = __expf(m[r] - mnew);
            m[r] = mnew;
            lsum[r] *= rs[r];
        }
        #pragma unroll
        for (int d = 0; d < 4; ++d)
            #pragma unroll
            for (int r = 0; r < 4; ++r)
                acc[d][r] *= rs[r];

        float lt[4] = {0.f, 0.f, 0.f, 0.f};
        #pragma unroll
        for (int nf = 0; nf < 4; ++nf)
            #pragma unroll
            for (int r = 0; r < 4; ++r) {
                const float p = __expf(s[nf][r] - m[r]);
                lt[r] += p;
                Pb[wave][lq * 4 + r][nf * 16 + l16] = f2b(p);
            }
        #pragma unroll
        for (int o = 1; o < 16; o <<= 1)
            #pragma unroll
            for (int r = 0; r < 4; ++r)
                lt[r] += __shfl_xor(lt[r], o, 64);
        #pragma unroll
        for (int r = 0; r < 4; ++r) lsum[r] += lt[r];

        // P (C-layout) -> per-wave LDS -> A-fragments (same-wave DS ordering)
        bf16x8 pf0 = *(const bf16x8*)&Pb[wave][l16][lq * 8];
        bf16x8 pf1 = *(const bf16x8*)&Pb[wave][l16][32 + lq * 8];

        #pragma unroll
        for (int d = 0; d < 4; ++d) {
            bf16x8 vf0 = *(const bf16x8*)(vh + (size_t)(d * 16 + l16) * S_LEN + sk0 + lq * 8);
            bf16x8 vf1 = *(const bf16x8*)(vh + (size_t)(d * 16 + l16) * S_LEN + sk0 + 32 + lq * 8);
            acc[d] = __builtin_amdgcn_mfma_f32_16x16x32_bf16(pf0, vf0, acc[d], 0, 0, 0);
            acc[d] = __builtin_amdgcn_mfma_f32_16x16x32_bf16(pf1, vf1, acc[d], 0, 0, 0);
        }
    }

    const float gate = (mask_logits[h] > 0.0f) ? 1.0f : 0.0f;
    #pragma unroll
    for (int r = 0; r < 4; ++r) {
        const float inv = gate / lsum[r];
        const int row = qb + lq * 4 + r;
        #pragma unroll
        for (int d = 0; d < 4; ++d)
            z[(size_t)row * D_MODEL + h * 64 + d * 16 + l16] = f2b(acc[d][r] * inv);
    }
}

// ---------------- launcher ----------------
extern "C" void kernel_launch(void* const* d_in, const int* in_sizes, int n_in,
                              void* d_out, int out_size, void* d_ws, size_t ws_size,
                              hipStream_t stream) {
    const float* resid_pre  = (const float*)d_in[0];
    const float* ln1_w      = (const float*)d_in[1];
    const float* ln1_b      = (const float*)d_in[2];
    const float* W_Q        = (const float*)d_in[3];
    const float* b_Q        = (const float*)d_in[4];
    const float* W_K        = (const float*)d_in[5];
    const float* b_K        = (const float*)d_in[6];
    const float* W_V        = (const float*)d_in[7];
    const float* b_V        = (const float*)d_in[8];
    const float* W_O        = (const float*)d_in[9];
    const float* b_O        = (const float*)d_in[10];
    const float* mask_logits= (const float*)d_in[11];
    const float* ln2_w      = (const float*)d_in[12];
    const float* ln2_b      = (const float*)d_in[13];
    const float* W_in       = (const float*)d_in[14];
    const float* b_in       = (const float*)d_in[15];
    const float* W_out      = (const float*)d_in[16];
    const float* b_out      = (const float*)d_in[17];

    char* p = (char*)d_ws;
    u16* WT_qkv = (u16*)p; p += (size_t)N_QKV * D_MODEL * 2;        // [3072][1024]
    u16* WT_O   = (u16*)p; p += (size_t)D_MODEL * D_MODEL * 2;      // [1024][1024]
    u16* WT_in  = (u16*)p; p += (size_t)F_MLP * D_MODEL * 2;        // [4096][1024]
    u16* WT_out = (u16*)p; p += (size_t)D_MODEL * F_MLP * 2;        // [1024][4096]
    float* qkvb = (float*)p; p += (size_t)N_QKV * 4;
    u16* xln    = (u16*)p; p += (size_t)S_LEN * D_MODEL * 2;
    u16* qk     = (u16*)p; p += (size_t)S_LEN * QK_LD * 2;          // Q(scaled) | K
    u16* vTb    = (u16*)p; p += (size_t)D_MODEL * S_LEN * 2;        // V transposed
    u16* zb     = (u16*)p; p += (size_t)S_LEN * D_MODEL * 2;
    float* rmid = (float*)p; p += (size_t)S_LEN * D_MODEL * 4;
    u16* mb     = (u16*)p; p += (size_t)S_LEN * D_MODEL * 2;
    u16* hb     = (u16*)p; p += (size_t)S_LEN * F_MLP * 2;

    dim3 tb(32, 8, 1);
    concat_bias<<<12, 256, 0, stream>>>(b_Q, b_K, b_V, qkvb);
    transpose_f32_bf16<<<dim3(2, 32, 16), tb, 0, stream>>>(W_Q, WT_qkv,                    1024, 64, 1024, 65536L, 64);
    transpose_f32_bf16<<<dim3(2, 32, 16), tb, 0, stream>>>(W_K, WT_qkv + 1024 * D_MODEL,   1024, 64, 1024, 65536L, 64);
    transpose_f32_bf16<<<dim3(2, 32, 16), tb, 0, stream>>>(W_V, WT_qkv + 2048 * D_MODEL,   1024, 64, 1024, 65536L, 64);
    transpose_f32_bf16<<<dim3(32, 32, 1), tb, 0, stream>>>(W_O,  WT_O,   1024, 1024, 1024, 0L, 0);
    transpose_f32_bf16<<<dim3(128, 32, 1), tb, 0, stream>>>(W_in, WT_in,  1024, 4096, 1024, 0L, 0);
    transpose_f32_bf16<<<dim3(32, 128, 1), tb, 0, stream>>>(W_out, WT_out, 4096, 1024, 4096, 0L, 0);

    layernorm_bf16<<<S_LEN, 256, 0, stream>>>(resid_pre, ln1_w, ln1_b, xln);

    gemm_bt<0><<<dim3(N_QKV / 128, S_LEN / 128), 256, 0, stream>>>(xln, WT_qkv, qkvb, nullptr, qk, vTb, S_LEN, N_QKV, D_MODEL);

    attn_kernel<<<dim3(512), 256, 0, stream>>>(qk, vTb, mask_logits, zb);

    gemm_bt<1><<<dim3(D_MODEL / 128, S_LEN / 128), 256, 0, stream>>>(zb, WT_O, b_O, resid_pre, rmid, nullptr, S_LEN, D_MODEL, D_MODEL);

    layernorm_bf16<<<S_LEN, 256, 0, stream>>>(rmid, ln2_w, ln2_b, mb);

    gemm_bt<2><<<dim3(F_MLP / 128, S_LEN / 128), 256, 0, stream>>>(mb, WT_in, b_in, nullptr, hb, nullptr, S_LEN, F_MLP, D_MODEL);

    gemm_bt<1><<<dim3(D_MODEL / 128, S_LEN / 128), 256, 0, stream>>>(hb, WT_out, b_out, rmid, (float*)d_out, nullptr, S_LEN, D_MODEL, F_MLP);
}

// Round 3
// 228.490 us; speedup vs baseline: 1.6962x; 1.2682x over previous
//
#include <hip/hip_runtime.h>
#include <math.h>

typedef unsigned short u16;
typedef __attribute__((ext_vector_type(8))) short bf16x8;
typedef __attribute__((ext_vector_type(4))) float f32x4;

#define S_LEN 2048
#define D_MODEL 1024
#define N_HEADS 16
#define D_HEAD 64
#define F_MLP 4096
#define N_QKV 3072
#define QK_LD 2048

__device__ __forceinline__ u16 f2b(float f) {
    union { float f; unsigned u; } x; x.f = f;
    unsigned r = x.u + 0x7fffu + ((x.u >> 16) & 1u);
    return (u16)(r >> 16);
}

__device__ __forceinline__ void gload_lds16(const u16* g, u16* l) {
    __builtin_amdgcn_global_load_lds((const __attribute__((address_space(1))) unsigned int*)g,
                                     (__attribute__((address_space(3))) unsigned int*)l, 16, 0, 0);
}

// ---------------- bias concat: [b_Q | b_K | b_V] -> qkvb[3072] ----------------
__global__ void concat_bias(const float* __restrict__ bq, const float* __restrict__ bk,
                            const float* __restrict__ bv, float* __restrict__ out) {
    int i = blockIdx.x * 256 + threadIdx.x;
    float v = (i < 1024) ? bq[i] : (i < 2048) ? bk[i - 1024] : bv[i - 2048];
    out[i] = v;
}

// ---------------- transpose f32 [R][C] -> bf16 [C][out_ld>=R], batched ----------------
__global__ void transpose_f32_bf16(const float* __restrict__ in, u16* __restrict__ out,
                                   int R, int C, int out_ld, long in_bstride, int out_brow) {
    __shared__ float t[32][33];
    int b = blockIdx.z;
    const float* src = in + (long)b * in_bstride;
    u16* dst = out + (long)b * out_brow * out_ld;
    int c0 = blockIdx.x * 32, r0 = blockIdx.y * 32;
    int tx = threadIdx.x, ty = threadIdx.y;   // 32 x 8
    #pragma unroll
    for (int i = 0; i < 32; i += 8)
        t[ty + i][tx] = src[(long)(r0 + ty + i) * C + c0 + tx];
    __syncthreads();
    #pragma unroll
    for (int i = 0; i < 32; i += 8)
        dst[(long)(c0 + ty + i) * out_ld + r0 + tx] = f2b(t[tx][ty + i]);
}

// ---------------- layernorm f32 [S][1024] -> bf16, one block per row ----------------
__global__ __launch_bounds__(256) void layernorm_bf16(const float* __restrict__ x,
                                                      const float* __restrict__ w,
                                                      const float* __restrict__ b,
                                                      u16* __restrict__ out) {
    int row = blockIdx.x, tid = threadIdx.x;
    const float4* xr = (const float4*)(x + (long)row * D_MODEL);
    float4 v = xr[tid];
    float s = v.x + v.y + v.z + v.w;
    float ss = v.x * v.x + v.y * v.y + v.z * v.z + v.w * v.w;
    #pragma unroll
    for (int o = 1; o < 64; o <<= 1) { s += __shfl_xor(s, o, 64); ss += __shfl_xor(ss, o, 64); }
    __shared__ float sh[8];
    int wave = tid >> 6, lane = tid & 63;
    if (lane == 0) { sh[wave] = s; sh[4 + wave] = ss; }
    __syncthreads();
    s = sh[0] + sh[1] + sh[2] + sh[3];
    ss = sh[4] + sh[5] + sh[6] + sh[7];
    float mu = s * (1.0f / D_MODEL);
    float var = ss * (1.0f / D_MODEL) - mu * mu;
    float rstd = rsqrtf(var + 1e-5f);
    float4 wv = ((const float4*)w)[tid];
    float4 bv = ((const float4*)b)[tid];
    u16 o4[4];
    o4[0] = f2b((v.x - mu) * rstd * wv.x + bv.x);
    o4[1] = f2b((v.y - mu) * rstd * wv.y + bv.y);
    o4[2] = f2b((v.z - mu) * rstd * wv.z + bv.z);
    o4[3] = f2b((v.w - mu) * rstd * wv.w + bv.w);
    *(ushort4*)(out + (long)row * D_MODEL + tid * 4) = *(ushort4*)o4;
}

// ---------------- split-K reduce: out = p0+p1+p2+p3 + bias + addend (all f32, [2048][1024]) ----
__global__ __launch_bounds__(256) void reduce_split4(const float* __restrict__ p,
                                                     const float* __restrict__ bias,
                                                     const float* __restrict__ addend,
                                                     float* __restrict__ out) {
    const size_t i = (size_t)blockIdx.x * 256 + threadIdx.x;     // float4 index
    const size_t MN4 = (size_t)S_LEN * D_MODEL / 4;
    const float4* p4 = (const float4*)p;
    float4 v0 = p4[i], v1 = p4[i + MN4], v2 = p4[i + 2 * MN4], v3 = p4[i + 3 * MN4];
    float4 b4 = ((const float4*)bias)[i & (D_MODEL / 4 - 1)];
    float4 a4 = ((const float4*)addend)[i];
    float4 o;
    o.x = v0.x + v1.x + v2.x + v3.x + b4.x + a4.x;
    o.y = v0.y + v1.y + v2.y + v3.y + b4.y + a4.y;
    o.z = v0.z + v1.z + v2.z + v3.z + b4.z + a4.z;
    o.w = v0.w + v1.w + v2.w + v3.w + b4.w + a4.w;
    ((float4*)out)[i] = o;
}

// ---------------- GEMM: C[M][N] = A[M][K](bf16) * BT[N][K](bf16)^T ----------------
// Double-buffered LDS prefetch; XCD-swizzled 1D grid (x: N-tiles, y: M-tiles, z: K-splits).
// MODE 0: QKV special — cols [0,2048) -> Cout bf16 (ld 2048), Q part scaled by 0.125;
//                        cols [2048,3072) -> vt transposed: vt[col-2048][row]. bias added.
// MODE 1: partial f32: Cout[z*M*N + row*N + col] = acc (bias/addend in reduce)
// MODE 2: out bf16 = gelu_tanh(acc + bias)
template <int MODE>
__global__ __launch_bounds__(256) void gemm_bt(const u16* __restrict__ A,
                                               const u16* __restrict__ BT,
                                               const float* __restrict__ bias,
                                               void* __restrict__ Cout,
                                               u16* __restrict__ vt,
                                               int M, int N, int K, int kb,
                                               int gx, int gy) {
    __shared__ u16 As[2][128 * 32];
    __shared__ u16 Bs[2][128 * 32];

    // bijective XCD swizzle (gridDim.x divisible by 8)
    const int lin = blockIdx.x;
    const int q = gridDim.x >> 3;
    const int swz = (lin & 7) * q + (lin >> 3);
    const int bx = swz % gx;
    const int rest = swz / gx;
    const int by = rest % gy;
    const int bz = rest / gy;

    const int bm = by * 128, bn = bx * 128;
    const int k0base = bz * kb;
    const int tid = threadIdx.x;
    const int wave = tid >> 6, lane = tid & 63;
    const int wm = (wave >> 1) * 64, wn = (wave & 1) * 64;
    const int l16 = lane & 15, lq = lane >> 4;
    const int srow = lane >> 2, scol = (lane & 3) * 8;   // 16B/lane, 16 rows x 32 cols per chunk

    f32x4 acc[4][4] = {};

    auto stage = [&](int buf, int kk) {
        #pragma unroll
        for (int c = 0; c < 2; ++c) {
            const int rbase = (wave * 2 + c) * 16;
            gload_lds16(A  + (size_t)(bm + rbase + srow) * K + kk + scol, &As[buf][rbase * 32]);
            gload_lds16(BT + (size_t)(bn + rbase + srow) * K + kk + scol, &Bs[buf][rbase * 32]);
        }
    };

    const int nk = kb >> 5;
    stage(0, k0base);
    __syncthreads();

    int buf = 0;
    for (int t = 0; t < nk; ++t) {
        if (t + 1 < nk) stage(buf ^ 1, k0base + (t + 1) * 32);   // prefetch in flight under compute
        bf16x8 af[4], bf[4];
        #pragma unroll
        for (int i = 0; i < 4; ++i) {
            af[i] = *(const bf16x8*)&As[buf][(wm + i * 16 + l16) * 32 + lq * 8];
            bf[i] = *(const bf16x8*)&Bs[buf][(wn + i * 16 + l16) * 32 + lq * 8];
        }
        #pragma unroll
        for (int i = 0; i < 4; ++i)
            #pragma unroll
            for (int j = 0; j < 4; ++j)
                acc[i][j] = __builtin_amdgcn_mfma_f32_16x16x32_bf16(af[i], bf[j], acc[i][j], 0, 0, 0);
        __syncthreads();                                          // drains prefetch + read-done
        buf ^= 1;
    }

    #pragma unroll
    for (int i = 0; i < 4; ++i) {
        const int row = bm + wm + i * 16 + lq * 4;
        #pragma unroll
        for (int j = 0; j < 4; ++j) {
            const int col = bn + wn + j * 16 + l16;
            if (MODE == 0) {
                const float bcol = bias[col];
                if (col < 2048) {
                    const float sc = (col < 1024) ? 0.125f : 1.0f;
                    #pragma unroll
                    for (int r = 0; r < 4; ++r)
                        ((u16*)Cout)[(size_t)(row + r) * QK_LD + col] = f2b((acc[i][j][r] + bcol) * sc);
                } else {
                    u16 tmp[4];
                    #pragma unroll
                    for (int r = 0; r < 4; ++r) tmp[r] = f2b(acc[i][j][r] + bcol);
                    *(ushort4*)(vt + (size_t)(col - 2048) * S_LEN + row) = *(const ushort4*)tmp;
                }
            } else if (MODE == 1) {
                float* out = (float*)Cout + (size_t)bz * M * N;
                #pragma unroll
                for (int r = 0; r < 4; ++r)
                    out[(size_t)(row + r) * N + col] = acc[i][j][r];
            } else {
                const float bcol = bias[col];
                #pragma unroll
                for (int r = 0; r < 4; ++r) {
                    float v = acc[i][j][r] + bcol;
                    float g_ = 0.5f * v * (1.0f + tanhf(0.7978845608028654f * (v + 0.044715f * v * v * v)));
                    ((u16*)Cout)[(size_t)(row + r) * N + col] = f2b(g_);
                }
            }
        }
    }
}

// ---------------- causal flash attention, wave-independent, no barriers ----------------
// qk bf16 [S][2048]: cols [0,1024)=Q*0.125 (scale pre-folded), [1024,2048)=K
// vT bf16 [1024][S]: row h*64+dh, col s
// z  bf16 [S][1024]
__global__ __launch_bounds__(256) void attn_kernel(const u16* __restrict__ qk,
                                                   const u16* __restrict__ vT,
                                                   const float* __restrict__ mask_logits,
                                                   u16* __restrict__ z) {
    const int tid = threadIdx.x;
    const int wave = tid >> 6, lane = tid & 63;
    const int l16 = lane & 15, lq = lane >> 4;
    const int b = blockIdx.x;
    const int h = b & 15, g = b >> 4;                 // g in [0,32)
    int qi = (wave == 0) ? g : (wave == 1) ? (63 - g) : (wave == 2) ? (64 + g) : (127 - g);
    const int qb = qi * 16;
    const int QC = h * 64, KC = 1024 + h * 64;
    const u16* vh = vT + (size_t)(h * 64) * S_LEN;

    __shared__ u16 Pb[4][16][72];                     // per-wave P tile, padded

    bf16x8 qf[2];
    #pragma unroll
    for (int kc = 0; kc < 2; ++kc)
        qf[kc] = *(const bf16x8*)(qk + (size_t)(qb + l16) * QK_LD + QC + kc * 32 + lq * 8);

    f32x4 acc[4] = {};
    float m[4], lsum[4];
    #pragma unroll
    for (int r = 0; r < 4; ++r) { m[r] = -3.0e38f; lsum[r] = 0.0f; }

    const int nt = (qb + 16 + 63) >> 6;               // 64-key tiles
    for (int t = 0; t < nt; ++t) {
        const int sk0 = t << 6;

        f32x4 s[4];
        #pragma unroll
        for (int nf = 0; nf < 4; ++nf) {
            f32x4 a = {};
            #pragma unroll
            for (int kc = 0; kc < 2; ++kc) {
                bf16x8 kf = *(const bf16x8*)(qk + (size_t)(sk0 + nf * 16 + l16) * QK_LD + KC + kc * 32 + lq * 8);
                a = __builtin_amdgcn_mfma_f32_16x16x32_bf16(qf[kc], kf, a, 0, 0, 0);
            }
            s[nf] = a;
        }

        if (t == nt - 1) {
            #pragma unroll
            for (int nf = 0; nf < 4; ++nf) {
                const int sk = sk0 + nf * 16 + l16;
                #pragma unroll
                for (int r = 0; r < 4; ++r) {
                    const int qrow = qb + lq * 4 + r;
                    s[nf][r] = (sk <= qrow) ? s[nf][r] : -3.0e38f;
                }
            }
        }

        float mt[4];
        #pragma unroll
        for (int r = 0; r < 4; ++r)
            mt[r] = fmaxf(fmaxf(s[0][r], s[1][r]), fmaxf(s[2][r], s[3][r]));
        #pragma unroll
        for (int o = 1; o < 16; o <<= 1)
            #pragma unroll
            for (int r = 0; r < 4; ++r)
                mt[r] = fmaxf(mt[r], __shfl_xor(mt[r], o, 64));

        float rs[4];
        #pragma unroll
        for (int r = 0; r < 4; ++r) {
            const float mnew = fmaxf(m[r], mt[r]);
            rs[r] = __expf(m[r] - mnew);
            m[r] = mnew;
            lsum[r] *= rs[r];
        }
        #pragma unroll
        for (int d = 0; d < 4; ++d)
            #pragma unroll
            for (int r = 0; r < 4; ++r)
                acc[d][r] *= rs[r];

        float lt[4] = {0.f, 0.f, 0.f, 0.f};
        #pragma unroll
        for (int nf = 0; nf < 4; ++nf)
            #pragma unroll
            for (int r = 0; r < 4; ++r) {
                const float p = __expf(s[nf][r] - m[r]);
                lt[r] += p;
                Pb[wave][lq * 4 + r][nf * 16 + l16] = f2b(p);
            }
        #pragma unroll
        for (int o = 1; o < 16; o <<= 1)
            #pragma unroll
            for (int r = 0; r < 4; ++r)
                lt[r] += __shfl_xor(lt[r], o, 64);
        #pragma unroll
        for (int r = 0; r < 4; ++r) lsum[r] += lt[r];

        bf16x8 pf0 = *(const bf16x8*)&Pb[wave][l16][lq * 8];
        bf16x8 pf1 = *(const bf16x8*)&Pb[wave][l16][32 + lq * 8];

        #pragma unroll
        for (int d = 0; d < 4; ++d) {
            bf16x8 vf0 = *(const bf16x8*)(vh + (size_t)(d * 16 + l16) * S_LEN + sk0 + lq * 8);
            bf16x8 vf1 = *(const bf16x8*)(vh + (size_t)(d * 16 + l16) * S_LEN + sk0 + 32 + lq * 8);
            acc[d] = __builtin_amdgcn_mfma_f32_16x16x32_bf16(pf0, vf0, acc[d], 0, 0, 0);
            acc[d] = __builtin_amdgcn_mfma_f32_16x16x32_bf16(pf1, vf1, acc[d], 0, 0, 0);
        }
    }

    const float gate = (mask_logits[h] > 0.0f) ? 1.0f : 0.0f;
    #pragma unroll
    for (int r = 0; r < 4; ++r) {
        const float inv = gate / lsum[r];
        const int row = qb + lq * 4 + r;
        #pragma unroll
        for (int d = 0; d < 4; ++d)
            z[(size_t)row * D_MODEL + h * 64 + d * 16 + l16] = f2b(acc[d][r] * inv);
    }
}

// ---------------- launcher ----------------
extern "C" void kernel_launch(void* const* d_in, const int* in_sizes, int n_in,
                              void* d_out, int out_size, void* d_ws, size_t ws_size,
                              hipStream_t stream) {
    const float* resid_pre  = (const float*)d_in[0];
    const float* ln1_w      = (const float*)d_in[1];
    const float* ln1_b      = (const float*)d_in[2];
    const float* W_Q        = (const float*)d_in[3];
    const float* b_Q        = (const float*)d_in[4];
    const float* W_K        = (const float*)d_in[5];
    const float* b_K        = (const float*)d_in[6];
    const float* W_V        = (const float*)d_in[7];
    const float* b_V        = (const float*)d_in[8];
    const float* W_O        = (const float*)d_in[9];
    const float* b_O        = (const float*)d_in[10];
    const float* mask_logits= (const float*)d_in[11];
    const float* ln2_w      = (const float*)d_in[12];
    const float* ln2_b      = (const float*)d_in[13];
    const float* W_in       = (const float*)d_in[14];
    const float* b_in       = (const float*)d_in[15];
    const float* W_out      = (const float*)d_in[16];
    const float* b_out      = (const float*)d_in[17];

    char* p = (char*)d_ws;
    u16* WT_qkv = (u16*)p; p += (size_t)N_QKV * D_MODEL * 2;        // [3072][1024]
    u16* WT_O   = (u16*)p; p += (size_t)D_MODEL * D_MODEL * 2;      // [1024][1024]
    u16* WT_in  = (u16*)p; p += (size_t)F_MLP * D_MODEL * 2;        // [4096][1024]
    u16* WT_out = (u16*)p; p += (size_t)D_MODEL * F_MLP * 2;        // [1024][4096]
    float* qkvb = (float*)p; p += (size_t)N_QKV * 4;
    u16* xln    = (u16*)p; p += (size_t)S_LEN * D_MODEL * 2;
    u16* qk     = (u16*)p; p += (size_t)S_LEN * QK_LD * 2;          // Q(scaled) | K
    u16* vTb    = (u16*)p; p += (size_t)D_MODEL * S_LEN * 2;        // V transposed
    u16* zb     = (u16*)p; p += (size_t)S_LEN * D_MODEL * 2;
    float* rmid = (float*)p; p += (size_t)S_LEN * D_MODEL * 4;
    u16* mb     = (u16*)p; p += (size_t)S_LEN * D_MODEL * 2;
    u16* hb     = (u16*)p; p += (size_t)S_LEN * F_MLP * 2;
    float* pbuf = (float*)p; p += (size_t)4 * S_LEN * D_MODEL * 4;  // split-K partials (32 MB)

    dim3 tb(32, 8, 1);
    concat_bias<<<12, 256, 0, stream>>>(b_Q, b_K, b_V, qkvb);
    transpose_f32_bf16<<<dim3(2, 32, 16), tb, 0, stream>>>(W_Q, WT_qkv,                    1024, 64, 1024, 65536L, 64);
    transpose_f32_bf16<<<dim3(2, 32, 16), tb, 0, stream>>>(W_K, WT_qkv + 1024 * D_MODEL,   1024, 64, 1024, 65536L, 64);
    transpose_f32_bf16<<<dim3(2, 32, 16), tb, 0, stream>>>(W_V, WT_qkv + 2048 * D_MODEL,   1024, 64, 1024, 65536L, 64);
    transpose_f32_bf16<<<dim3(32, 32, 1), tb, 0, stream>>>(W_O,  WT_O,   1024, 1024, 1024, 0L, 0);
    transpose_f32_bf16<<<dim3(128, 32, 1), tb, 0, stream>>>(W_in, WT_in,  1024, 4096, 1024, 0L, 0);
    transpose_f32_bf16<<<dim3(32, 128, 1), tb, 0, stream>>>(W_out, WT_out, 4096, 1024, 4096, 0L, 0);

    layernorm_bf16<<<S_LEN, 256, 0, stream>>>(resid_pre, ln1_w, ln1_b, xln);

    // QKV: [2048 x 3072 x 1024], grid 24x16 = 384
    gemm_bt<0><<<dim3(384), 256, 0, stream>>>(xln, WT_qkv, qkvb, qk, vTb,
                                              S_LEN, N_QKV, D_MODEL, D_MODEL, 24, 16);

    attn_kernel<<<dim3(512), 256, 0, stream>>>(qk, vTb, mask_logits, zb);

    // W_O: [2048 x 1024 x 1024], split-K x4 -> grid 8x16x4 = 512
    gemm_bt<1><<<dim3(512), 256, 0, stream>>>(zb, WT_O, nullptr, pbuf, nullptr,
                                              S_LEN, D_MODEL, D_MODEL, 256, 8, 16);
    reduce_split4<<<2048, 256, 0, stream>>>(pbuf, b_O, resid_pre, rmid);

    layernorm_bf16<<<S_LEN, 256, 0, stream>>>(rmid, ln2_w, ln2_b, mb);

    // MLP1: [2048 x 4096 x 1024], grid 32x16 = 512
    gemm_bt<2><<<dim3(512), 256, 0, stream>>>(mb, WT_in, b_in, hb, nullptr,
                                              S_LEN, F_MLP, D_MODEL, D_MODEL, 32, 16);

    // MLP2: [2048 x 1024 x 4096], split-K x4 -> grid 8x16x4 = 512
    gemm_bt<1><<<dim3(512), 256, 0, stream>>>(hb, WT_out, nullptr, pbuf, nullptr,
                                              S_LEN, D_MODEL, F_MLP, 1024, 8, 16);
    reduce_split4<<<2048, 256, 0, stream>>>(pbuf, b_out, rmid, (float*)d_out);
}